// Round 20
// baseline (121.145 us; speedup 1.0000x reference)
//
#include <hip/hip_runtime.h>
#include <stdint.h>

#define MDIM 16384
#define NDIM 16384
#define DDIM 256
#define NSPLIT 4
#define NSTRIP 4096
#define BM 64
#define NT 32          // n-tiles of 128 cols (4 waves x private 32 cols)

typedef __attribute__((ext_vector_type(16))) float f32x16;
typedef __attribute__((ext_vector_type(8))) int i32x8;
typedef __attribute__((ext_vector_type(4))) int i32x4;

#define SC1 0x7F7F7F7F   // E8M0 scale bytes = 127 -> 2^0 = 1.0 (any opsel byte)

// ---------------- ws layout (bytes) ----------------
static constexpr size_t COLPART_OFF = 0;                       // 2 MB (1024 blk x 256 col float2)
static constexpr size_t SCAL_OFF    = 2ull << 20;              // c, thr=-104/c
static constexpr size_t AX_OFF      = SCAL_OFF + 1024u;        // 64 KB (M floats, raw nsq)
static constexpr size_t BXR_OFF     = AX_OFF + 64u * 1024u;    // 64 KB (N packed {resid,nsq} bf16)
static constexpr size_t BXM_OFF     = BXR_OFF + 64u * 1024u;   // 1 KB (N/64 group nsq-min bits)
static constexpr size_t X8_OFF      = 4ull << 20;              // 2 MB fp4, A-tiled (4MB reserved)
static constexpr size_t B8_OFF      = 8ull << 20;              // 2 MB fp4, B-tiled (4MB+slack)
static constexpr size_t NUMP_OFF    = 13ull << 20;
static constexpr size_t DENP_OFF    = NUMP_OFF + (size_t)NSPLIT * MDIM * 4u;

__device__ inline unsigned short f2bf_rne(float f) {
    uint32_t u = __builtin_bit_cast(uint32_t, f);
    u += 0x7fffu + ((u >> 16) & 1u);
    return (unsigned short)(u >> 16);
}

// fp4 e2m1 RNE quantize: grid {0,.5,1,1.5,2,3,4,6}, midpoint thresholds
__device__ inline unsigned e2m1q(float v) {
    const float a = __builtin_fabsf(v);
    unsigned m = (unsigned)(a >= 0.25f) + (unsigned)(a >= 0.75f) + (unsigned)(a >= 1.25f)
               + (unsigned)(a >= 1.75f) + (unsigned)(a >= 2.5f)  + (unsigned)(a >= 3.5f)
               + (unsigned)(a >= 5.0f);
    return m | ((__builtin_bit_cast(unsigned, v) >> 28) & 8u);
}

__device__ inline i32x8 pad8(i32x4 v) {
    return (i32x8){v[0], v[1], v[2], v[3], 0, 0, 0, 0};   // fp4 operands use low 4 regs
}

// K3 (x + X + colstats merged; NO scal dependency -- raw-value fp4 quantization).
// 16 rows/block; lane owns one row (l>>4) and 16 consecutive k (q=l&15).
// Tiles (0.5 B/el, el e at byte e>>1 nibble e&1, same bijection A and B):
//  A (x rows): byte = (r>>7)*16384 + ks64*4096 + ((r>>5)&3)*1024 + lh*512 + (r&31)*16 + eb*8
//  B (X rows): byte = (r>>6)*8192  + ks64*2048 + lh*1024 + (r&63)*16 + eb*8
// Row norms stored RAW (nsq); X rows also pack {resid, nsq} bf16, atomicMin the
// 64-row-group nsq bits (positive-float uint order; 0xAA poison = huge -> valid init;
// idempotent), and accumulate per-block column sum/sumsq partials for Scott's rule.
__global__ void k3_prep(const float* __restrict__ x, const float* __restrict__ X,
                        unsigned char* __restrict__ x8T, unsigned char* __restrict__ B8T,
                        float* __restrict__ ax,
                        const float* __restrict__ resid, unsigned int* __restrict__ bxrp,
                        unsigned int* __restrict__ bxminu, float2* __restrict__ colpart) {
    __shared__ float sC[4][256], qC[4][256];
    const int l    = threadIdx.x & 63;
    const int wv   = threadIdx.x >> 6;
    const bool isB = blockIdx.x >= (MDIM / 16);
    const int bB   = blockIdx.x - (MDIM / 16);
    const int row  = (isB ? bB : blockIdx.x) * 16 + wv * 4 + (l >> 4);
    const int q    = l & 15;
    const float* src = isB ? X : x;

    float vs[16];
    {
        const float* pr = src + (size_t)row * DDIM + q * 16;
#pragma unroll
        for (int i = 0; i < 4; ++i) {
            float4 v = *(const float4*)(pr + i * 4);
            vs[4 * i] = v.x; vs[4 * i + 1] = v.y; vs[4 * i + 2] = v.z; vs[4 * i + 3] = v.w;
        }
    }
    float nsq = 0.f;
#pragma unroll
    for (int j = 0; j < 16; ++j) nsq += vs[j] * vs[j];
#pragma unroll
    for (int o = 1; o < 16; o <<= 1) nsq += __shfl_xor(nsq, o);

    unsigned w0 = 0, w1 = 0;
#pragma unroll
    for (int i = 0; i < 4; ++i) {
        w0 |= (e2m1q(vs[2 * i]) | (e2m1q(vs[2 * i + 1]) << 4)) << (8 * i);
        w1 |= (e2m1q(vs[8 + 2 * i]) | (e2m1q(vs[9 + 2 * i]) << 4)) << (8 * i);
    }
    const uint2 u = make_uint2(w0, w1);

    const int ks64 = q >> 2, lh = (q >> 1) & 1, eb = q & 1;
    if (isB) {
        const size_t off = (size_t)(row >> 6) * 8192 + ks64 * 2048 + lh * 1024
                         + (row & 63) * 16 + eb * 8;
        *(uint2*)(B8T + off) = u;
        if (q == 0) {
            bxrp[row] = ((unsigned int)f2bf_rne(resid[row]) << 16) | f2bf_rne(nsq);
            atomicMin(&bxminu[row >> 6], __builtin_bit_cast(unsigned int, nsq));
        }
        // ---- column sum/sumsq partials over this block's 16 rows ----
        float sv[16], qv[16];
#pragma unroll
        for (int j = 0; j < 16; ++j) { sv[j] = vs[j]; qv[j] = vs[j] * vs[j]; }
#pragma unroll
        for (int o = 16; o <= 32; o <<= 1)
#pragma unroll
            for (int j = 0; j < 16; ++j) {
                sv[j] += __shfl_xor(sv[j], o);
                qv[j] += __shfl_xor(qv[j], o);
            }
        if ((l >> 4) == 0) {
#pragma unroll
            for (int j = 0; j < 16; ++j) { sC[wv][q * 16 + j] = sv[j]; qC[wv][q * 16 + j] = qv[j]; }
        }
        __syncthreads();
        const int t = threadIdx.x;
        colpart[bB * 256 + t] = make_float2(sC[0][t] + sC[1][t] + sC[2][t] + sC[3][t],
                                            qC[0][t] + qC[1][t] + qC[2][t] + qC[3][t]);
    } else {
        const size_t off = (size_t)(row >> 7) * 16384 + ks64 * 4096 + ((row >> 5) & 3) * 1024
                         + lh * 512 + (row & 31) * 16 + eb * 8;
        *(uint2*)(x8T + off) = u;
        if (q == 0) ax[row] = nsq;
    }
}

// K2: finalize Scott's rule from 1024 column partials; scal = {c, thr=-104/c}
__global__ void k2_finalize(const float2* __restrict__ part, float* __restrict__ scal) {
    const int t = threadIdx.x;
    float s = 0.f, sq = 0.f;
#pragma unroll 8
    for (int b = 0; b < 1024; ++b) {
        float2 v = part[b * 256 + t];
        s += v.x; sq += v.y;
    }
    const float n = (float)NDIM;
    float var = (sq - s * s / n) / (n - 1.0f);
    float sd  = sqrtf(fmaxf(var, 0.f));
    __shared__ float red[256];
    red[t] = sd;
    __syncthreads();
    for (int o = 128; o > 0; o >>= 1) {
        if (t < o) red[t] += red[t + o];
        __syncthreads();
    }
    if (t == 0) {
        float h = (red[0] / 256.0f) * exp2f(log2f(n) * (-1.0f / (DDIM + 4.0f)));
        float c = 1.0f / (2.0f * h * h);
        scal[0] = c;
        scal[1] = -104.0f / c;
    }
}

// K4: MX-fp4, 4 waves/SIMD (the fp4 A-file makes the r13 occupancy plan fit:
// aF 32 + acc 32 + bF 16 + misc ~ 110 <= 128 regs -> launch_bounds(256,4)).
// BM=64: 4 waves share 64 A-rows, own 32-col slices of a 128-col tile; grid 1024
// = 4 blocks/CU = 16 waves/CU. Per step: 1 dwordx4 B-load (ring-4 depth-2,
// compiler vmcnt), 2 MFMA 32x32x64 fp4. Raw-scale numerics: acc = dot_raw;
// gate: 2*max(acc) - min nsqA - min nsqB < thr(-104/c); fallback exact-ish path.
__global__ __launch_bounds__(256, 4)
void k4_main(const unsigned char* __restrict__ x8T, const unsigned char* __restrict__ B8T,
             const float* __restrict__ ax, const unsigned int* __restrict__ bxrp,
             const unsigned int* __restrict__ bxminu, const float* __restrict__ scal,
             float* __restrict__ nump, float* __restrict__ denp) {
    __shared__ float ldsBxm[NSTRIP / 64];   // 256 B (per-64-col-group raw nsq min)
    __shared__ float ldsAcc[2 * BM];        // 512 B rare-path accumulator

    const int tid  = threadIdx.x;
    const int lane = tid & 63;
    const int wv   = tid >> 6;
    const int l31  = lane & 31;
    const int lhi  = lane >> 5;

    const int f  = blockIdx.x;                // 1024 blocks, bijective XCD swizzle
    const int sw = (f & 7) * 128 + (f >> 3);
    const int mt = sw & 255;
    const int by = sw >> 8;                   // 0..3
    const int m0 = mt * BM;
    const int n0 = by * NSTRIP;

    const float c   = scal[0];
    const float thr = scal[1];
    if (tid < NSTRIP / 64)
        ldsBxm[tid] = __builtin_bit_cast(float, bxminu[(n0 >> 6) + tid]);
    if (tid < 2 * BM) ldsAcc[tid] = 0.f;

    // gate scalar: min raw nsq over the block's 64 rows
    float axmin = ax[m0 + lane];
#pragma unroll
    for (int o = 1; o < 64; o <<= 1) axmin = fminf(axmin, __shfl_xor(axmin, o));

    // ---- A fragments resident (fp4: i32x4 per (rf,ks) = 32 VGPR total) ----
    const unsigned char* Ab = x8T + (size_t)(mt >> 1) * 16384 + (mt & 1) * 2048
                            + lhi * 512 + l31 * 16;
    i32x4 aF[2][4];
#pragma unroll
    for (int rf = 0; rf < 2; ++rf)
#pragma unroll
        for (int ks = 0; ks < 4; ++ks)
            aF[rf][ks] = *(const i32x4*)(Ab + ks * 4096 + rf * 1024);

    // ---- B: ring of 4 i32x4 slots, depth-2 prefetch, compiler-managed waits ----
    const unsigned char* Bb = B8T + (size_t)((n0 >> 6) + (wv >> 1)) * 8192
                            + lhi * 1024 + ((wv & 1) * 32 + l31) * 16;
    i32x4 bF[4];
#pragma unroll
    for (int s = 0; s < 2; ++s)
        bF[s] = *(const i32x4*)(Bb + (size_t)(s >> 2) * 16384 + (s & 3) * 2048);

    __syncthreads();                        // ldsBxm/ldsAcc visible

    f32x16 acc[2];

#pragma unroll 1
    for (int nt = 0; nt < NT; ++nt) {
#pragma unroll
        for (int ks = 0; ks < 4; ++ks) {   // step s = nt*4+ks (K-step 64)
            // prefetch step s+2 into slot (ks+2)&3 (beyond-end reads land in slack)
            {
                const int sp = nt * 4 + ks + 2;
                bF[(ks + 2) & 3] = *(const i32x4*)(Bb + (size_t)(sp >> 2) * 16384
                                                   + (size_t)(sp & 3) * 2048);
            }
            __builtin_amdgcn_sched_barrier(0);
            __builtin_amdgcn_s_setprio(1);
            {
                const i32x8 b8 = pad8(bF[ks & 3]);
#pragma unroll
                for (int rf = 0; rf < 2; ++rf) {
                    if (ks == 0)
                        acc[rf] = __builtin_amdgcn_mfma_scale_f32_32x32x64_f8f6f4(
                            pad8(aF[rf][ks]), b8, (f32x16)(0.f), 4, 4, 0, SC1, 0, SC1);
                    else
                        acc[rf] = __builtin_amdgcn_mfma_scale_f32_32x32x64_f8f6f4(
                            pad8(aF[rf][ks]), b8, acc[rf], 4, 4, 0, SC1, 0, SC1);
                }
            }
            __builtin_amdgcn_s_setprio(0);
            __builtin_amdgcn_sched_barrier(0);

            if (ks == 3) {
                // ---- underflow-gated tile finish (wave's 32 cols in one 64-group) ----
                const float bxmin = ldsBxm[nt * 2 + (wv >> 1)];
                float m = -1e30f;
#pragma unroll
                for (int i = 0; i < 2; ++i)
#pragma unroll
                    for (int r = 0; r < 16; r += 4) {
                        f32x16 v = acc[i];
                        m = fmaxf(m, fmaxf(fmaxf(v[r], v[r + 1]), fmaxf(v[r + 2], v[r + 3])));
                    }
                if (!__all(2.f * m - axmin - bxmin < thr)) {
                    // fallback path (never taken for this data)
                    const unsigned int pk = bxrp[n0 + nt * 128 + wv * 32 + l31];
                    const float bxv = __builtin_bit_cast(float, pk << 16);
                    const float rv  = __builtin_bit_cast(float, pk & 0xffff0000u);
#pragma unroll
                    for (int rf = 0; rf < 2; ++rf)
#pragma unroll
                        for (int r = 0; r < 16; ++r) {
                            const int row = rf * 32 + (r & 3) + 8 * (r >> 2) + 4 * lhi;
                            const float axv = ax[m0 + row];
                            const float arg = fminf(c * (2.f * acc[rf][r] - axv - bxv), 0.f);
                            const float w = expf(arg);
                            float nv = w * rv, dv = w;
#pragma unroll
                            for (int o = 1; o < 32; o <<= 1) { nv += __shfl_xor(nv, o); dv += __shfl_xor(dv, o); }
                            if (l31 == 0) {
                                atomicAdd(&ldsAcc[row * 2 + 0], nv);
                                atomicAdd(&ldsAcc[row * 2 + 1], dv);
                            }
                        }
                }
            }
        }
    }

    __syncthreads();
    if (tid < BM) {
        nump[by * MDIM + m0 + tid] = ldsAcc[tid * 2 + 0];
        denp[by * MDIM + m0 + tid] = ldsAcc[tid * 2 + 1];
    }
}

__global__ void k5_div(const float* __restrict__ nump, const float* __restrict__ denp,
                       float* __restrict__ out) {
    const int i = blockIdx.x * 256 + threadIdx.x;
    float n = 0.f, d = 0.f;
#pragma unroll
    for (int s = 0; s < NSPLIT; ++s) { n += nump[s * MDIM + i]; d += denp[s * MDIM + i]; }
    out[i] = n / (d + 1e-8f);
}

extern "C" void kernel_launch(void* const* d_in, const int* in_sizes, int n_in,
                              void* d_out, int out_size, void* d_ws, size_t ws_size,
                              hipStream_t stream) {
    const float* x     = (const float*)d_in[0];
    const float* X     = (const float*)d_in[1];
    const float* resid = (const float*)d_in[2];
    float* out = (float*)d_out;

    char* w = (char*)d_ws;
    float2* colpart      = (float2*)(w + COLPART_OFF);
    float*  scal         = (float*)(w + SCAL_OFF);
    float*  ax           = (float*)(w + AX_OFF);
    unsigned int* bxrp   = (unsigned int*)(w + BXR_OFF);
    unsigned int* bxminu = (unsigned int*)(w + BXM_OFF);
    unsigned char* x8    = (unsigned char*)(w + X8_OFF);
    unsigned char* B8    = (unsigned char*)(w + B8_OFF);
    float* nump          = (float*)(w + NUMP_OFF);
    float* denp          = (float*)(w + DENP_OFF);

    k3_prep<<<(MDIM + NDIM) / 16, 256, 0, stream>>>(x, X, x8, B8, ax, resid, bxrp, bxminu, colpart);
    k2_finalize<<<1, 256, 0, stream>>>(colpart, scal);
    k4_main<<<1024, 256, 0, stream>>>(x8, B8, ax, bxrp, bxminu, scal, nump, denp);
    k5_div<<<MDIM / 256, 256, 0, stream>>>(nump, denp, out);
}

// Round 21
// 77.726 us; speedup vs baseline: 1.5586x; 1.5586x over previous
//
#include <hip/hip_runtime.h>
#include <stdint.h>

#define MDIM 16384
#define NDIM 16384
#define DDIM 256
#define NSPLIT 4
#define NSTRIP 4096
#define BM 64
#define NT 32          // n-tiles of 128 cols (4 waves x private 32 cols)

typedef __attribute__((ext_vector_type(16))) float f32x16;
typedef __attribute__((ext_vector_type(8))) int i32x8;
typedef __attribute__((ext_vector_type(4))) int i32x4;

#define SC1 0x7F7F7F7F   // E8M0 scale bytes = 127 -> 2^0 = 1.0 (any opsel byte)

// ---------------- ws layout (bytes) ----------------
static constexpr size_t COLPART_OFF = 0;                       // 2 MB (1024 blk x 256 col float2)
static constexpr size_t COLP2_OFF   = 2ull << 20;              // 128 KB (64 x 256 float2)
static constexpr size_t SCAL_OFF    = COLP2_OFF + (128u << 10);// c, thr=-104/c
static constexpr size_t AX_OFF      = SCAL_OFF + 1024u;        // 64 KB (M floats, raw nsq)
static constexpr size_t BXR_OFF     = AX_OFF + 64u * 1024u;    // 64 KB (N packed {resid,nsq} bf16)
static constexpr size_t BXM_OFF     = BXR_OFF + 64u * 1024u;   // 1 KB (N/64 group nsq-min bits)
static constexpr size_t X8_OFF      = 4ull << 20;              // 2 MB fp4, A-tiled (4MB reserved)
static constexpr size_t B8_OFF      = 8ull << 20;              // 2 MB fp4, B-tiled (4MB+slack)
static constexpr size_t NUMP_OFF    = 13ull << 20;
static constexpr size_t DENP_OFF    = NUMP_OFF + (size_t)NSPLIT * MDIM * 4u;

__device__ inline unsigned short f2bf_rne(float f) {
    uint32_t u = __builtin_bit_cast(uint32_t, f);
    u += 0x7fffu + ((u >> 16) & 1u);
    return (unsigned short)(u >> 16);
}

// fp4 e2m1 RNE quantize: grid {0,.5,1,1.5,2,3,4,6}, midpoint thresholds
__device__ inline unsigned e2m1q(float v) {
    const float a = __builtin_fabsf(v);
    unsigned m = (unsigned)(a >= 0.25f) + (unsigned)(a >= 0.75f) + (unsigned)(a >= 1.25f)
               + (unsigned)(a >= 1.75f) + (unsigned)(a >= 2.5f)  + (unsigned)(a >= 3.5f)
               + (unsigned)(a >= 5.0f);
    return m | ((__builtin_bit_cast(unsigned, v) >> 28) & 8u);
}

__device__ inline i32x8 pad8(i32x4 v) {
    return (i32x8){v[0], v[1], v[2], v[3], 0, 0, 0, 0};   // fp4 operands use low 4 regs
}

// K3 (x + X + colstats merged; NO scal dependency -- raw-value fp4 quantization).
// See r19 notes. Row norms stored RAW (nsq); X rows also pack {resid,nsq} bf16,
// atomicMin 64-row-group nsq bits (poison-safe, idempotent), and write per-block
// column sum/sumsq partials for Scott's rule.
__global__ void k3_prep(const float* __restrict__ x, const float* __restrict__ X,
                        unsigned char* __restrict__ x8T, unsigned char* __restrict__ B8T,
                        float* __restrict__ ax,
                        const float* __restrict__ resid, unsigned int* __restrict__ bxrp,
                        unsigned int* __restrict__ bxminu, float2* __restrict__ colpart) {
    __shared__ float sC[4][256], qC[4][256];
    const int l    = threadIdx.x & 63;
    const int wv   = threadIdx.x >> 6;
    const bool isB = blockIdx.x >= (MDIM / 16);
    const int bB   = blockIdx.x - (MDIM / 16);
    const int row  = (isB ? bB : blockIdx.x) * 16 + wv * 4 + (l >> 4);
    const int q    = l & 15;
    const float* src = isB ? X : x;

    float vs[16];
    {
        const float* pr = src + (size_t)row * DDIM + q * 16;
#pragma unroll
        for (int i = 0; i < 4; ++i) {
            float4 v = *(const float4*)(pr + i * 4);
            vs[4 * i] = v.x; vs[4 * i + 1] = v.y; vs[4 * i + 2] = v.z; vs[4 * i + 3] = v.w;
        }
    }
    float nsq = 0.f;
#pragma unroll
    for (int j = 0; j < 16; ++j) nsq += vs[j] * vs[j];
#pragma unroll
    for (int o = 1; o < 16; o <<= 1) nsq += __shfl_xor(nsq, o);

    unsigned w0 = 0, w1 = 0;
#pragma unroll
    for (int i = 0; i < 4; ++i) {
        w0 |= (e2m1q(vs[2 * i]) | (e2m1q(vs[2 * i + 1]) << 4)) << (8 * i);
        w1 |= (e2m1q(vs[8 + 2 * i]) | (e2m1q(vs[9 + 2 * i]) << 4)) << (8 * i);
    }
    const uint2 u = make_uint2(w0, w1);

    const int ks64 = q >> 2, lh = (q >> 1) & 1, eb = q & 1;
    if (isB) {
        const size_t off = (size_t)(row >> 6) * 8192 + ks64 * 2048 + lh * 1024
                         + (row & 63) * 16 + eb * 8;
        *(uint2*)(B8T + off) = u;
        if (q == 0) {
            bxrp[row] = ((unsigned int)f2bf_rne(resid[row]) << 16) | f2bf_rne(nsq);
            atomicMin(&bxminu[row >> 6], __builtin_bit_cast(unsigned int, nsq));
        }
        // ---- column sum/sumsq partials over this block's 16 rows ----
        float sv[16], qv[16];
#pragma unroll
        for (int j = 0; j < 16; ++j) { sv[j] = vs[j]; qv[j] = vs[j] * vs[j]; }
#pragma unroll
        for (int o = 16; o <= 32; o <<= 1)
#pragma unroll
            for (int j = 0; j < 16; ++j) {
                sv[j] += __shfl_xor(sv[j], o);
                qv[j] += __shfl_xor(qv[j], o);
            }
        if ((l >> 4) == 0) {
#pragma unroll
            for (int j = 0; j < 16; ++j) { sC[wv][q * 16 + j] = sv[j]; qC[wv][q * 16 + j] = qv[j]; }
        }
        __syncthreads();
        const int t = threadIdx.x;
        colpart[bB * 256 + t] = make_float2(sC[0][t] + sC[1][t] + sC[2][t] + sC[3][t],
                                            qC[0][t] + qC[1][t] + qC[2][t] + qC[3][t]);
    } else {
        const size_t off = (size_t)(row >> 7) * 16384 + ks64 * 4096 + ((row >> 5) & 3) * 1024
                         + lh * 512 + (row & 31) * 16 + eb * 8;
        *(uint2*)(x8T + off) = u;
        if (q == 0) ax[row] = nsq;
    }
}

// K2a: 64 blocks; block g reduces colpart blocks [16g, 16g+16) (coalesced reads)
__global__ void k2a_reduce(const float2* __restrict__ part, float2* __restrict__ part2) {
    const int t = threadIdx.x;
    const int g = blockIdx.x;
    float s = 0.f, sq = 0.f;
#pragma unroll
    for (int b = 0; b < 16; ++b) {
        float2 v = part[(g * 16 + b) * 256 + t];
        s += v.x; sq += v.y;
    }
    part2[g * 256 + t] = make_float2(s, sq);
}

// K2b: finalize Scott's rule from 64 partials; scal = {c, thr=-104/c}
__global__ void k2b_finalize(const float2* __restrict__ part2, float* __restrict__ scal) {
    const int t = threadIdx.x;
    float s = 0.f, sq = 0.f;
#pragma unroll 8
    for (int b = 0; b < 64; ++b) {
        float2 v = part2[b * 256 + t];
        s += v.x; sq += v.y;
    }
    const float n = (float)NDIM;
    float var = (sq - s * s / n) / (n - 1.0f);
    float sd  = sqrtf(fmaxf(var, 0.f));
    __shared__ float red[256];
    red[t] = sd;
    __syncthreads();
    for (int o = 128; o > 0; o >>= 1) {
        if (t < o) red[t] += red[t + o];
        __syncthreads();
    }
    if (t == 0) {
        float h = (red[0] / 256.0f) * exp2f(log2f(n) * (-1.0f / (DDIM + 4.0f)));
        float c = 1.0f / (2.0f * h * h);
        scal[0] = c;
        scal[1] = -104.0f / c;
    }
}

// K4: MX-fp4, 4 waves/SIMD (aF 32 + acc 32 + bF 16 + misc ~ 110 <= 128 regs ->
// launch_bounds(256,4)). BM=64: 4 waves share 64 A-rows, own 32-col slices of a
// 128-col tile; grid 1024 = 4 blocks/CU = 16 waves/CU. Per step: 1 dwordx4 B-load
// (ring-4 depth-2, compiler vmcnt), 2 MFMA 32x32x64 fp4. Raw-scale numerics:
// gate 2*max(acc) - min nsqA - min nsqB < thr(-104/c); fallback path for any input.
__global__ __launch_bounds__(256, 4)
void k4_main(const unsigned char* __restrict__ x8T, const unsigned char* __restrict__ B8T,
             const float* __restrict__ ax, const unsigned int* __restrict__ bxrp,
             const unsigned int* __restrict__ bxminu, const float* __restrict__ scal,
             float* __restrict__ nump, float* __restrict__ denp) {
    __shared__ float ldsBxm[NSTRIP / 64];   // 256 B (per-64-col-group raw nsq min)
    __shared__ float ldsAcc[2 * BM];        // 512 B rare-path accumulator

    const int tid  = threadIdx.x;
    const int lane = tid & 63;
    const int wv   = tid >> 6;
    const int l31  = lane & 31;
    const int lhi  = lane >> 5;

    const int f  = blockIdx.x;                // 1024 blocks, bijective XCD swizzle
    const int sw = (f & 7) * 128 + (f >> 3);
    const int mt = sw & 255;
    const int by = sw >> 8;                   // 0..3
    const int m0 = mt * BM;
    const int n0 = by * NSTRIP;

    const float c   = scal[0];
    const float thr = scal[1];
    if (tid < NSTRIP / 64)
        ldsBxm[tid] = __builtin_bit_cast(float, bxminu[(n0 >> 6) + tid]);
    if (tid < 2 * BM) ldsAcc[tid] = 0.f;

    // gate scalar: min raw nsq over the block's 64 rows
    float axmin = ax[m0 + lane];
#pragma unroll
    for (int o = 1; o < 64; o <<= 1) axmin = fminf(axmin, __shfl_xor(axmin, o));

    // ---- A fragments resident (fp4: i32x4 per (rf,ks) = 32 VGPR total) ----
    const unsigned char* Ab = x8T + (size_t)(mt >> 1) * 16384 + (mt & 1) * 2048
                            + lhi * 512 + l31 * 16;
    i32x4 aF[2][4];
#pragma unroll
    for (int rf = 0; rf < 2; ++rf)
#pragma unroll
        for (int ks = 0; ks < 4; ++ks)
            aF[rf][ks] = *(const i32x4*)(Ab + ks * 4096 + rf * 1024);

    // ---- B: ring of 4 i32x4 slots, depth-2 prefetch, compiler-managed waits ----
    const unsigned char* Bb = B8T + (size_t)((n0 >> 6) + (wv >> 1)) * 8192
                            + lhi * 1024 + ((wv & 1) * 32 + l31) * 16;
    i32x4 bF[4];
#pragma unroll
    for (int s = 0; s < 2; ++s)
        bF[s] = *(const i32x4*)(Bb + (size_t)(s >> 2) * 16384 + (s & 3) * 2048);

    __syncthreads();                        // ldsBxm/ldsAcc visible

    f32x16 acc[2];

#pragma unroll 1
    for (int nt = 0; nt < NT; ++nt) {
#pragma unroll
        for (int ks = 0; ks < 4; ++ks) {   // step s = nt*4+ks (K-step 64)
            // prefetch step s+2 into slot (ks+2)&3 (beyond-end reads land in slack)
            {
                const int sp = nt * 4 + ks + 2;
                bF[(ks + 2) & 3] = *(const i32x4*)(Bb + (size_t)(sp >> 2) * 16384
                                                   + (size_t)(sp & 3) * 2048);
            }
            __builtin_amdgcn_sched_barrier(0);
            __builtin_amdgcn_s_setprio(1);
            {
                const i32x8 b8 = pad8(bF[ks & 3]);
#pragma unroll
                for (int rf = 0; rf < 2; ++rf) {
                    if (ks == 0)
                        acc[rf] = __builtin_amdgcn_mfma_scale_f32_32x32x64_f8f6f4(
                            pad8(aF[rf][ks]), b8, (f32x16)(0.f), 4, 4, 0, SC1, 0, SC1);
                    else
                        acc[rf] = __builtin_amdgcn_mfma_scale_f32_32x32x64_f8f6f4(
                            pad8(aF[rf][ks]), b8, acc[rf], 4, 4, 0, SC1, 0, SC1);
                }
            }
            __builtin_amdgcn_s_setprio(0);
            __builtin_amdgcn_sched_barrier(0);

            if (ks == 3) {
                // ---- underflow-gated tile finish (wave's 32 cols in one 64-group) ----
                const float bxmin = ldsBxm[nt * 2 + (wv >> 1)];
                float m = -1e30f;
#pragma unroll
                for (int i = 0; i < 2; ++i)
#pragma unroll
                    for (int r = 0; r < 16; r += 4) {
                        f32x16 v = acc[i];
                        m = fmaxf(m, fmaxf(fmaxf(v[r], v[r + 1]), fmaxf(v[r + 2], v[r + 3])));
                    }
                if (!__all(2.f * m - axmin - bxmin < thr)) {
                    // fallback path (never taken for this data)
                    const unsigned int pk = bxrp[n0 + nt * 128 + wv * 32 + l31];
                    const float bxv = __builtin_bit_cast(float, pk << 16);
                    const float rv  = __builtin_bit_cast(float, pk & 0xffff0000u);
#pragma unroll
                    for (int rf = 0; rf < 2; ++rf)
#pragma unroll
                        for (int r = 0; r < 16; ++r) {
                            const int row = rf * 32 + (r & 3) + 8 * (r >> 2) + 4 * lhi;
                            const float axv = ax[m0 + row];
                            const float arg = fminf(c * (2.f * acc[rf][r] - axv - bxv), 0.f);
                            const float w = expf(arg);
                            float nv = w * rv, dv = w;
#pragma unroll
                            for (int o = 1; o < 32; o <<= 1) { nv += __shfl_xor(nv, o); dv += __shfl_xor(dv, o); }
                            if (l31 == 0) {
                                atomicAdd(&ldsAcc[row * 2 + 0], nv);
                                atomicAdd(&ldsAcc[row * 2 + 1], dv);
                            }
                        }
                }
            }
        }
    }

    __syncthreads();
    if (tid < BM) {
        nump[by * MDIM + m0 + tid] = ldsAcc[tid * 2 + 0];
        denp[by * MDIM + m0 + tid] = ldsAcc[tid * 2 + 1];
    }
}

__global__ void k5_div(const float* __restrict__ nump, const float* __restrict__ denp,
                       float* __restrict__ out) {
    const int i = blockIdx.x * 256 + threadIdx.x;
    float n = 0.f, d = 0.f;
#pragma unroll
    for (int s = 0; s < NSPLIT; ++s) { n += nump[s * MDIM + i]; d += denp[s * MDIM + i]; }
    out[i] = n / (d + 1e-8f);
}

extern "C" void kernel_launch(void* const* d_in, const int* in_sizes, int n_in,
                              void* d_out, int out_size, void* d_ws, size_t ws_size,
                              hipStream_t stream) {
    const float* x     = (const float*)d_in[0];
    const float* X     = (const float*)d_in[1];
    const float* resid = (const float*)d_in[2];
    float* out = (float*)d_out;

    char* w = (char*)d_ws;
    float2* colpart      = (float2*)(w + COLPART_OFF);
    float2* colp2        = (float2*)(w + COLP2_OFF);
    float*  scal         = (float*)(w + SCAL_OFF);
    float*  ax           = (float*)(w + AX_OFF);
    unsigned int* bxrp   = (unsigned int*)(w + BXR_OFF);
    unsigned int* bxminu = (unsigned int*)(w + BXM_OFF);
    unsigned char* x8    = (unsigned char*)(w + X8_OFF);
    unsigned char* B8    = (unsigned char*)(w + B8_OFF);
    float* nump          = (float*)(w + NUMP_OFF);
    float* denp          = (float*)(w + DENP_OFF);

    k3_prep<<<(MDIM + NDIM) / 16, 256, 0, stream>>>(x, X, x8, B8, ax, resid, bxrp, bxminu, colpart);
    k2a_reduce<<<64, 256, 0, stream>>>(colpart, colp2);
    k2b_finalize<<<1, 256, 0, stream>>>(colp2, scal);
    k4_main<<<1024, 256, 0, stream>>>(x8, B8, ax, bxrp, bxminu, scal, nump, denp);
    k5_div<<<MDIM / 256, 256, 0, stream>>>(nump, denp, out);
}